// Round 18
// baseline (436.941 us; speedup 1.0000x reference)
//
#include <hip/hip_runtime.h>
#include <hip/hip_bf16.h>

#define NN 50000
#define NE 800000
#define HID 64
#define EPSV 1e-5f
#define NBLK 196            // ceil(NN/256)

typedef __attribute__((ext_vector_type(8))) short bf16x8;
typedef __attribute__((ext_vector_type(4))) float f32x4;
typedef __attribute__((ext_vector_type(4))) int int4v;

__device__ __forceinline__ ushort f2b(float f) {
    union { __hip_bfloat16 b; ushort u; } c;
    c.b = __float2bfloat16(f);
    return c.u;
}
__device__ __forceinline__ float b2f(ushort u) {
    return __uint_as_float(((unsigned int)u) << 16);
}

// ---------------- fused prep: all weight cvts + icnt zero + bn zero ----------------
__global__ void prep_all_kernel(
    const float* __restrict__ W1, const float* __restrict__ W2,
    const float* __restrict__ Wl0, const float* __restrict__ Wr0, const float* __restrict__ rW0,
    const float* __restrict__ Wl1, const float* __restrict__ Wr1,
    const float* __restrict__ Wl2, const float* __restrict__ Wr2,
    ushort* __restrict__ W1b, ushort* __restrict__ W2b,
    ushort* __restrict__ wnb, int* __restrict__ icnt, float* __restrict__ bnbuf)
{
    int i = blockIdx.x * 256 + threadIdx.x;
    if      (i < 16384)  W1b[i] = f2b(W1[i]);
    else if (i < 32768)  W2b[i - 16384] = f2b(W2[i - 16384]);
    else if (i < 40960)  wnb[i - 32768] = f2b(Wl0[i - 32768]);
    else if (i < 49152)  wnb[i - 32768] = f2b(Wr0[i - 40960]);
    else if (i < 57344)  wnb[i - 32768] = f2b(rW0[i - 49152]);
    else if (i < 61440)  wnb[i - 32768] = f2b(Wl1[i - 57344]);
    else if (i < 65536)  wnb[i - 32768] = f2b(Wr1[i - 61440]);
    else if (i < 69632)  wnb[i - 32768] = f2b(Wl2[i - 65536]);
    else if (i < 73728)  wnb[i - 32768] = f2b(Wr2[i - 69632]);
    else if (i < 123728) icnt[i - 73728] = 0;
    else if (i < 124112) bnbuf[i - 123728] = 0.f;
}

// ---------------- CSR build ----------------
__global__ void count_kernel(const int* __restrict__ tgt, int* __restrict__ icnt) {
    int e = blockIdx.x * 256 + threadIdx.x;
    if (e < NE) atomicAdd(&icnt[tgt[e]], 1);
}

__global__ void scanA_kernel(const int* __restrict__ icnt, int* __restrict__ off,
                             int* __restrict__ bsum) {
    __shared__ int s[256];
    const int t = threadIdx.x;
    const int i = blockIdx.x * 256 + t;
    int v = (i < NN) ? icnt[i] : 0;
    s[t] = v;
    __syncthreads();
    for (int d = 1; d < 256; d <<= 1) {
        int x = (t >= d) ? s[t - d] : 0;
        __syncthreads();
        s[t] += x;
        __syncthreads();
    }
    if (i < NN) off[i] = s[t];             // inclusive, block-local
    if (t == 255) bsum[blockIdx.x] = s[255];
}

__global__ void scanB_kernel(const int* __restrict__ icnt, const int* __restrict__ bsum,
                             int* __restrict__ off, int* __restrict__ woff) {
    __shared__ int red[256];
    const int t = threadIdx.x, bid = blockIdx.x;
    int s = 0;
    for (int j = t; j < bid; j += 256) s += bsum[j];
    red[t] = s;
    __syncthreads();
    for (int d = 128; d > 0; d >>= 1) {
        if (t < d) red[t] += red[t + d];
        __syncthreads();
    }
    const int bpre = red[0];
    const int i = bid * 256 + t;
    if (i < NN) {
        int e = off[i] - icnt[i] + bpre;
        off[i] = e;
        woff[i] = e;
        if (i == NN - 1) off[NN] = NE;
    }
}

__global__ void fill_kernel(const int* __restrict__ src, const int* __restrict__ tgt,
                            int* __restrict__ woff, int* __restrict__ ebuf) {
    int e = blockIdx.x * 256 + threadIdx.x;
    if (e < NE) {
        int p = atomicAdd(&woff[tgt[e]], 1);
        ebuf[p] = src[e];
    }
}

// ---------------- layer-0 projection: staged x-tile, 3 segs fused ----------------
__global__ __launch_bounds__(256) void proj0_mfma_kernel(
    const float* __restrict__ x,
    const ushort* __restrict__ w0, const ushort* __restrict__ w1,
    const ushort* __restrict__ w2,
    const float* __restrict__ bias1, const float* __restrict__ bias2,
    ushort* __restrict__ xb, float* __restrict__ pre, float* __restrict__ res)
{
    __shared__ ushort xt[128 * 128];    // 32 KB swizzled bf16 x-tile
    __shared__ float sC[128][65];
    const int tid = threadIdx.x;
    const int wv = tid >> 6, lane = tid & 63;
    const int l15 = lane & 15, l4 = lane >> 4;
    const int n0 = blockIdx.x * 128;

    {
        const int rloc = tid >> 1;
        int row = n0 + rloc; if (row > NN - 1) row = NN - 1;
        const int c0 = (tid & 1) * 64;
        #pragma unroll
        for (int gq = 0; gq < 8; gq++) {
            int c = c0 + gq * 8;
            float4 f0 = *(const float4*)&x[(long)row * 128 + c];
            float4 f1 = *(const float4*)&x[(long)row * 128 + c + 4];
            union { ushort u[8]; int4v v; } a;
            a.u[0] = f2b(f0.x); a.u[1] = f2b(f0.y); a.u[2] = f2b(f0.z); a.u[3] = f2b(f0.w);
            a.u[4] = f2b(f1.x); a.u[5] = f2b(f1.y); a.u[6] = f2b(f1.z); a.u[7] = f2b(f1.w);
            int byte = rloc * 256 + ((c * 2) ^ ((rloc & 7) << 4));
            *(int4v*)((char*)xt + byte) = a.v;
        }
    }
    __syncthreads();

    for (int seg = 0; seg < 3; seg++) {
        const ushort* W = (seg == 0) ? w0 : ((seg == 1) ? w1 : w2);
        bf16x8 wf[4][4];
        #pragma unroll
        for (int n = 0; n < 4; n++)
            #pragma unroll
            for (int ks = 0; ks < 4; ks++)
                wf[n][ks] = *(const bf16x8*)&W[(n * 16 + l15) * 128 + ks * 32 + l4 * 8];

        f32x4 acc[2][4];
        #pragma unroll
        for (int m = 0; m < 2; m++)
            #pragma unroll
            for (int n = 0; n < 4; n++)
                acc[m][n] = (f32x4){0.f, 0.f, 0.f, 0.f};

        #pragma unroll
        for (int m = 0; m < 2; m++) {
            const int row = wv * 32 + m * 16 + l15;
            #pragma unroll
            for (int ks = 0; ks < 4; ks++) {
                int byte = row * 256 + ((ks * 64 + l4 * 16) ^ ((row & 7) << 4));
                bf16x8 a = *(const bf16x8*)((const char*)xt + byte);
                #pragma unroll
                for (int n = 0; n < 4; n++)
                    acc[m][n] = __builtin_amdgcn_mfma_f32_16x16x32_bf16(a, wf[n][ks], acc[m][n], 0, 0, 0);
            }
        }
        #pragma unroll
        for (int m = 0; m < 2; m++)
            #pragma unroll
            for (int n = 0; n < 4; n++)
                #pragma unroll
                for (int r = 0; r < 4; r++)
                    sC[wv * 32 + m * 16 + l4 * 4 + r][n * 16 + l15] = acc[m][n][r];
        __syncthreads();

        const int r = tid >> 1, ch = (tid & 1) * 32;
        const int node = n0 + r;
        if (node < NN) {
            if (seg == 0) {
                #pragma unroll
                for (int gq = 0; gq < 4; gq++) {
                    union { ushort u[8]; int4v v; } pk;
                    #pragma unroll
                    for (int j = 0; j < 8; j++)
                        pk.u[j] = f2b(sC[r][ch + gq * 8 + j]);
                    *(int4v*)&xb[(long)node * 64 + ch + gq * 8] = pk.v;
                }
            } else {
                float* O = (seg == 1) ? pre : res;
                const float* bp = (seg == 1) ? bias1 : bias2;
                #pragma unroll
                for (int gq = 0; gq < 8; gq++) {
                    int c = ch + gq * 4;
                    float4 v = make_float4(sC[r][c + 0] + bp[c + 0], sC[r][c + 1] + bp[c + 1],
                                           sC[r][c + 2] + bp[c + 2], sC[r][c + 3] + bp[c + 3]);
                    *(float4*)&O[(long)node * 64 + c] = v;
                }
            }
        }
        __syncthreads();
    }
}

// ---------------- gather v2.2: 8-edge-wide vectorized, 2048-block grid, hoisted self-term ----------------
__global__ __launch_bounds__(256) void gather_bn_kernel(
    const int* __restrict__ off, const int* __restrict__ ebuf,
    const ushort* __restrict__ xb,
    float* __restrict__ vbase,
    float* __restrict__ bnsum, float* __restrict__ bnsq)
{
    __shared__ float r1[4][64], r2[4][64];
    const int lane = threadIdx.x & 63;
    const int wid = __builtin_amdgcn_readfirstlane(threadIdx.x >> 6);
    const int eslot = lane >> 3;
    const int cg = lane & 7;
    float s8[8], q8[8];
    #pragma unroll
    for (int j = 0; j < 8; j++) { s8[j] = 0.f; q8[j] = 0.f; }

    for (int n = blockIdx.x * 4 + wid; n < NN; n += gridDim.x * 4) {
        const int a = off[n], b = off[n + 1];
        // hoist self-term load so its latency hides under the gather loop
        float4 p0, p1;
        if (eslot == 0) {
            p0 = *(const float4*)&vbase[(long)n * 64 + cg * 8];
            p1 = *(const float4*)&vbase[(long)n * 64 + cg * 8 + 4];
        }
        float acc[8];
        #pragma unroll
        for (int j = 0; j < 8; j++) acc[j] = 0.f;
        for (int p = a + eslot; p < b; p += 8) {
            int sidx = ebuf[p];
            union { int4v v; ushort u[8]; } cv;
            cv.v = *(const int4v*)&xb[(long)sidx * 64 + cg * 8];
            #pragma unroll
            for (int j = 0; j < 8; j++) acc[j] += b2f(cv.u[j]);
        }
        #pragma unroll
        for (int m = 8; m <= 32; m <<= 1)
            #pragma unroll
            for (int j = 0; j < 8; j++)
                acc[j] += __shfl_xor(acc[j], m);
        if (eslot == 0) {
            const float inv_deg = 1.0f / fmaxf((float)(b - a), 1.f);
            float v[8];
            v[0] = acc[0] * inv_deg + p0.x; v[1] = acc[1] * inv_deg + p0.y;
            v[2] = acc[2] * inv_deg + p0.z; v[3] = acc[3] * inv_deg + p0.w;
            v[4] = acc[4] * inv_deg + p1.x; v[5] = acc[5] * inv_deg + p1.y;
            v[6] = acc[6] * inv_deg + p1.z; v[7] = acc[7] * inv_deg + p1.w;
            *(float4*)&vbase[(long)n * 64 + cg * 8]     = make_float4(v[0], v[1], v[2], v[3]);
            *(float4*)&vbase[(long)n * 64 + cg * 8 + 4] = make_float4(v[4], v[5], v[6], v[7]);
            #pragma unroll
            for (int j = 0; j < 8; j++) { s8[j] += v[j]; q8[j] += v[j] * v[j]; }
        }
    }
    if (eslot == 0) {
        #pragma unroll
        for (int j = 0; j < 8; j++) {
            r1[wid][cg * 8 + j] = s8[j];
            r2[wid][cg * 8 + j] = q8[j];
        }
    }
    __syncthreads();
    if (threadIdx.x < 64) {
        float s = r1[0][lane] + r1[1][lane] + r1[2][lane] + r1[3][lane];
        float q = r2[0][lane] + r2[1][lane] + r2[2][lane] + r2[3][lane];
        atomicAdd(&bnsum[lane], s);
        atomicAdd(&bnsq[lane], q);
    }
}

// ---------------- fused: BN-apply(layer i) + proj(layer i+1) ----------------
__global__ __launch_bounds__(256) void apply_proj_kernel(
    const float* __restrict__ vIn,
    const float* __restrict__ resb,
    const float* __restrict__ bnsum, const float* __restrict__ bnsq,
    const float* __restrict__ g, const float* __restrict__ be,
    float* __restrict__ hout,
    const ushort* __restrict__ Wl, const ushort* __restrict__ Wr,
    const float* __restrict__ bias,
    ushort* __restrict__ xb, float* __restrict__ preOut)
{
    __shared__ float scs[64], shs[64];
    __shared__ ushort tile[128 * 72];
    __shared__ float sC[128][65];
    const int tid = threadIdx.x;
    const int n0 = blockIdx.x * 128;
    const int wv = tid >> 6, lane = tid & 63;
    const int l15 = lane & 15, l4 = lane >> 4;

    if (tid < 64) {
        const float inv_n = 1.0f / (float)NN;
        float mu = bnsum[tid] * inv_n;
        float var = bnsq[tid] * inv_n - mu * mu;
        float rstd = rsqrtf(var + EPSV);
        float sc = g[tid] * rstd;
        scs[tid] = sc;
        shs[tid] = be[tid] - mu * sc;
    }
    __syncthreads();

    {
        const int rloc = tid >> 1;
        const int n = n0 + rloc;
        const int ch = (tid & 1) * 32;
        if (n < NN) {
            #pragma unroll
            for (int gq = 0; gq < 4; gq++) {
                int c = ch + gq * 8;
                float4 v0 = *(const float4*)&vIn[(long)n * 64 + c];
                float4 v1 = *(const float4*)&vIn[(long)n * 64 + c + 4];
                float4 r0 = *(const float4*)&resb[(long)n * 64 + c];
                float4 r1 = *(const float4*)&resb[(long)n * 64 + c + 4];
                float o[8];
                o[0] = fmaxf(fmaf(v0.x, scs[c + 0], shs[c + 0]), 0.f) + r0.x;
                o[1] = fmaxf(fmaf(v0.y, scs[c + 1], shs[c + 1]), 0.f) + r0.y;
                o[2] = fmaxf(fmaf(v0.z, scs[c + 2], shs[c + 2]), 0.f) + r0.z;
                o[3] = fmaxf(fmaf(v0.w, scs[c + 3], shs[c + 3]), 0.f) + r0.w;
                o[4] = fmaxf(fmaf(v1.x, scs[c + 4], shs[c + 4]), 0.f) + r1.x;
                o[5] = fmaxf(fmaf(v1.y, scs[c + 5], shs[c + 5]), 0.f) + r1.y;
                o[6] = fmaxf(fmaf(v1.z, scs[c + 6], shs[c + 6]), 0.f) + r1.z;
                o[7] = fmaxf(fmaf(v1.w, scs[c + 7], shs[c + 7]), 0.f) + r1.w;
                *(float4*)&hout[(long)n * 64 + c]     = make_float4(o[0], o[1], o[2], o[3]);
                *(float4*)&hout[(long)n * 64 + c + 4] = make_float4(o[4], o[5], o[6], o[7]);
                union { ushort u[8]; int4v v; } pk;
                #pragma unroll
                for (int j = 0; j < 8; j++) pk.u[j] = f2b(o[j]);
                int byte = rloc * 144 + ((c * 2) ^ ((rloc & 7) << 4));
                *(int4v*)((char*)tile + byte) = pk.v;
            }
        }
    }
    __syncthreads();

    for (int seg = 0; seg < 2; seg++) {
        const ushort* W = seg ? Wr : Wl;
        bf16x8 wf[4][2];
        #pragma unroll
        for (int n = 0; n < 4; n++)
            #pragma unroll
            for (int ks = 0; ks < 2; ks++)
                wf[n][ks] = *(const bf16x8*)&W[(n * 16 + l15) * 64 + ks * 32 + l4 * 8];

        f32x4 acc[2][4];
        #pragma unroll
        for (int m = 0; m < 2; m++)
            #pragma unroll
            for (int n = 0; n < 4; n++)
                acc[m][n] = (f32x4){0.f, 0.f, 0.f, 0.f};

        #pragma unroll
        for (int m = 0; m < 2; m++) {
            const int row = wv * 32 + m * 16 + l15;
            #pragma unroll
            for (int ks = 0; ks < 2; ks++) {
                int byte = row * 144 + ((((ks * 32 + l4 * 8) * 2)) ^ ((row & 7) << 4));
                bf16x8 a = *(const bf16x8*)((const char*)tile + byte);
                #pragma unroll
                for (int n = 0; n < 4; n++)
                    acc[m][n] = __builtin_amdgcn_mfma_f32_16x16x32_bf16(a, wf[n][ks], acc[m][n], 0, 0, 0);
            }
        }
        #pragma unroll
        for (int m = 0; m < 2; m++)
            #pragma unroll
            for (int n = 0; n < 4; n++)
                #pragma unroll
                for (int r = 0; r < 4; r++)
                    sC[wv * 32 + m * 16 + l4 * 4 + r][n * 16 + l15] = acc[m][n][r];
        __syncthreads();

        const int r = tid >> 1, ch = (tid & 1) * 32;
        const int node = n0 + r;
        if (node < NN) {
            if (seg == 0) {
                #pragma unroll
                for (int gq = 0; gq < 4; gq++) {
                    union { ushort u[8]; int4v v; } pk;
                    #pragma unroll
                    for (int j = 0; j < 8; j++)
                        pk.u[j] = f2b(sC[r][ch + gq * 8 + j]);
                    *(int4v*)&xb[(long)node * 64 + ch + gq * 8] = pk.v;
                }
            } else {
                #pragma unroll
                for (int gq = 0; gq < 8; gq++) {
                    int c = ch + gq * 4;
                    float4 v = make_float4(sC[r][c + 0] + bias[c + 0], sC[r][c + 1] + bias[c + 1],
                                           sC[r][c + 2] + bias[c + 2], sC[r][c + 3] + bias[c + 3]);
                    *(float4*)&preOut[(long)node * 64 + c] = v;
                }
            }
        }
        __syncthreads();
    }
}

// ---------------- final BN apply -> hb (bf16) only ----------------
__global__ void apply_final_kernel(const float* __restrict__ vIn,
                                   const float* __restrict__ resb,
                                   const float* __restrict__ bnsum, const float* __restrict__ bnsq,
                                   const float* __restrict__ g, const float* __restrict__ be,
                                   ushort* __restrict__ hb)
{
    const float inv_n = 1.0f / (float)NN;
    const int stride = gridDim.x * 256;
    for (int i = blockIdx.x * 256 + threadIdx.x; i < NN * 16; i += stride) {
        int n = i >> 4;
        int c0 = (i & 15) * 4;
        float sc[4], sh[4];
        #pragma unroll
        for (int j = 0; j < 4; j++) {
            int c = c0 + j;
            float mu = bnsum[c] * inv_n;
            float var = bnsq[c] * inv_n - mu * mu;
            float rstd = rsqrtf(var + EPSV);
            sc[j] = g[c] * rstd;
            sh[j] = be[c] - mu * sc[j];
        }
        float4 v = *(const float4*)&vIn[(long)n * 64 + c0];
        float4 r = *(const float4*)&resb[(long)n * 64 + c0];
        union { ushort u[4]; uint2 v2; } p;
        p.u[0] = f2b(fmaxf(fmaf(v.x, sc[0], sh[0]), 0.f) + r.x);
        p.u[1] = f2b(fmaxf(fmaf(v.y, sc[1], sh[1]), 0.f) + r.y);
        p.u[2] = f2b(fmaxf(fmaf(v.z, sc[2], sh[2]), 0.f) + r.z);
        p.u[3] = f2b(fmaxf(fmaf(v.w, sc[3], sh[3]), 0.f) + r.w);
        *(uint2*)&hb[(long)n * 64 + c0] = p.v2;
    }
}

// ---------------- edge MLP: barrier-free wave strips, SWAPPED L1 (R15-measured, 66us) ----------------
#define NSTRIP 25000        // NE / 32
#define EMG 256
#define ZSTR 136            // z1 row stride in ushorts (272 B, 16B-aligned)

#define GATHER(ss)                                                        \
    do {                                                                  \
        int e0g = (ss) * 32;                                              \
        _Pragma("unroll")                                                 \
        for (int m = 0; m < 2; m++) {                                     \
            int e = e0g + m * 16 + l15;                                   \
            const ushort* hs = hb + (long)src[e] * 64;                    \
            const ushort* ht = hb + (long)tgt[e] * 64;                    \
            ga[m][0] = *(const bf16x8*)&hs[l4 * 8];                       \
            ga[m][1] = *(const bf16x8*)&hs[32 + l4 * 8];                  \
            ga[m][2] = *(const bf16x8*)&ht[l4 * 8];                       \
            ga[m][3] = *(const bf16x8*)&ht[32 + l4 * 8];                  \
        }                                                                 \
    } while (0)

__global__ __launch_bounds__(512) void edge_mlp_wave_kernel(
    const ushort* __restrict__ hb,
    const int* __restrict__ src, const int* __restrict__ tgt,
    const ushort* __restrict__ W1b, const ushort* __restrict__ W2b,
    const float* __restrict__ b1, const float* __restrict__ b2,
    const float* __restrict__ W3, const float* __restrict__ b3,
    float* __restrict__ out)
{
    __shared__ ushort wlds[32768];        // [layer][oc][k], 16B-chunk XOR swizzle
    __shared__ ushort z1[8][32 * ZSTR];   // wave-private Z1 slices

    const int tid = threadIdx.x;
    const int wid = tid >> 6, lane = tid & 63;
    const int l15 = lane & 15, l4 = lane >> 4;

    for (int c = tid; c < 4096; c += 512) {
        int layer = c >> 11, oc = (c >> 4) & 127, kc = c & 15;
        const ushort* Wsrc = layer ? W2b : W1b;
        int4v v = *(const int4v*)&Wsrc[oc * 128 + kc * 8];
        int byte = layer * 32768 + oc * 256 + ((kc * 16) ^ ((oc & 7) << 4));
        *(int4v*)((char*)wlds + byte) = v;
    }

    // L1 bias as oc-quads (swapped C-layout: row=oc=n*16+l4*4+r)
    float4 b1q[8];
    float b2v[8], w3v[8];
    #pragma unroll
    for (int n = 0; n < 8; n++) {
        b1q[n] = *(const float4*)&b1[n * 16 + l4 * 4];
        int oc = n * 16 + l15;
        b2v[n] = b2[oc]; w3v[n] = W3[oc];
    }
    const float b3v = b3[0];

    const int bid = blockIdx.x;
    const int q = NSTRIP / EMG, r = NSTRIP % EMG;    // 97, 168
    const int t0 = bid * q + (bid < r ? bid : r);
    const int nt = q + (bid < r ? 1 : 0);
    ushort* zw = z1[wid];

    bf16x8 ga[2][4];
    if (wid < nt) GATHER(t0 + wid);
    __syncthreads();                      // wlds ready (only barrier)

    for (int j = wid; j < nt; j += 8) {
        const int e0 = (t0 + j) * 32;

        // ---- layer 1 (SWAPPED operands): C col=edge, row=oc ----
        f32x4 acc[2][8];
        #pragma unroll
        for (int m = 0; m < 2; m++)
            #pragma unroll
            for (int n = 0; n < 8; n++)
                acc[m][n] = (f32x4){b1q[n].x, b1q[n].y, b1q[n].z, b1q[n].w};
        #pragma unroll
        for (int ks = 0; ks < 4; ks++) {
            bf16x8 wf[8];
            #pragma unroll
            for (int n = 0; n < 8; n++) {
                int oc = n * 16 + l15;
                int byte = oc * 256 + (((ks * 4 + l4) * 16) ^ ((oc & 7) << 4));
                wf[n] = *(const bf16x8*)((const char*)wlds + byte);
            }
            #pragma unroll
            for (int m = 0; m < 2; m++)
                #pragma unroll
                for (int n = 0; n < 8; n++)
                    acc[m][n] = __builtin_amdgcn_mfma_f32_16x16x32_bf16(wf[n], ga[m][ks], acc[m][n], 0, 0, 0);
        }
        // Z1 = relu(acc): lane holds 4 consecutive oc for ONE edge -> b64 writes
        #pragma unroll
        for (int m = 0; m < 2; m++)
            #pragma unroll
            for (int n = 0; n < 8; n++) {
                union { ushort u[4]; uint2 d; } pk;
                #pragma unroll
                for (int rr = 0; rr < 4; rr++)
                    pk.u[rr] = f2b(fmaxf(acc[m][n][rr], 0.f));
                *(uint2*)&zw[(m * 16 + l15) * ZSTR + n * 16 + l4 * 4] = pk.d;
            }

        if (j + 8 < nt) GATHER(t0 + j + 8);

        // ---- layer 2 (unswapped) ----
        f32x4 acc2[2][8];
        #pragma unroll
        for (int m = 0; m < 2; m++)
            #pragma unroll
            for (int n = 0; n < 8; n++)
                acc2[m][n] = (f32x4){b2v[n], b2v[n], b2v[n], b2v[n]};
        #pragma unroll
        for (int ks = 0; ks < 4; ks++) {
            bf16x8 wf[8];
            #pragma unroll
            for (int n = 0; n < 8; n++) {
                int oc = n * 16 + l15;
                int byte = 32768 + oc * 256 + (((ks * 4 + l4) * 16) ^ ((oc & 7) << 4));
                wf[n] = *(const bf16x8*)((const char*)wlds + byte);
            }
            bf16x8 a2[2];
            #pragma unroll
            for (int m = 0; m < 2; m++)
                a2[m] = *(const bf16x8*)&zw[(m * 16 + l15) * ZSTR + ks * 32 + l4 * 8];
            #pragma unroll
            for (int m = 0; m < 2; m++)
                #pragma unroll
                for (int n = 0; n < 8; n++)
                    acc2[m][n] = __builtin_amdgcn_mfma_f32_16x16x32_bf16(a2[m], wf[n], acc2[m][n], 0, 0, 0);
        }

        // ---- layer 3 ----
        #pragma unroll
        for (int m = 0; m < 2; m++) {
            float sv[4];
            #pragma unroll
            for (int rr = 0; rr < 4; rr++) {
                float s = 0.f;
                #pragma unroll
                for (int n = 0; n < 8; n++)
                    s = fmaf(fmaxf(acc2[m][n][rr], 0.f), w3v[n], s);
                s += __shfl_xor(s, 1);
                s += __shfl_xor(s, 2);
                s += __shfl_xor(s, 4);
                s += __shfl_xor(s, 8);
                sv[rr] = s + b3v;
            }
            if (l15 == 0)
                *(float4*)&out[e0 + m * 16 + l4 * 4] =
                    make_float4(sv[0], sv[1], sv[2], sv[3]);
        }
    }
}

// ---------------- launch ----------------
extern "C" void kernel_launch(void* const* d_in, const int* in_sizes, int n_in,
                              void* d_out, int out_size, void* d_ws, size_t ws_size,
                              hipStream_t stream)
{
    const float* x   = (const float*)d_in[0];
    const int*   ei  = (const int*)d_in[1];
    const int* src = ei;
    const int* tgt = ei + NE;
    const float* Wl0 = (const float*)d_in[2];
    const float* bl0 = (const float*)d_in[3];
    const float* Wr0 = (const float*)d_in[4];
    const float* g0  = (const float*)d_in[5];
    const float* be0 = (const float*)d_in[6];
    const float* rW0 = (const float*)d_in[7];
    const float* rb0 = (const float*)d_in[8];
    const float* Wl1 = (const float*)d_in[9];
    const float* bl1 = (const float*)d_in[10];
    const float* Wr1 = (const float*)d_in[11];
    const float* g1  = (const float*)d_in[12];
    const float* be1 = (const float*)d_in[13];
    const float* Wl2 = (const float*)d_in[14];
    const float* bl2 = (const float*)d_in[15];
    const float* Wr2 = (const float*)d_in[16];
    const float* g2  = (const float*)d_in[17];
    const float* be2 = (const float*)d_in[18];
    const float* W1  = (const float*)d_in[19];
    const float* b1  = (const float*)d_in[20];
    const float* W2  = (const float*)d_in[21];
    const float* b2  = (const float*)d_in[22];
    const float* W3  = (const float*)d_in[23];
    const float* b3  = (const float*)d_in[24];
    float* out = (float*)d_out;

    float* ws = (float*)d_ws;
    float*  pre  = ws;                           // [0, 3.2M)
    float*  res  = ws + 3200000;                 // [3.2M, 6.4M)
    float*  hbuf = ws + 6400000;                 // [6.4M, 9.6M)
    ushort* xb   = (ushort*)(ws + 9600256);      // floats [9600256, 11200256)
    ushort* hb   = (ushort*)(ws + 11200256);     // floats [11200256, 12800256)
    ushort* W1b  = (ushort*)(ws + 12800256);     // floats [12800256, 12808448)
    ushort* W2b  = W1b + 16384;                  // floats [12808448, 12816640)
    int*    icnt = (int*)(ws + 12816640);        // 50000
    int*    off  = icnt + 50000;                 // 50001 -> 12866640
    int*    woff = off + 50001;                  // 50000 -> 12916641
    int*    ebuf = woff + 50000;                 // 800000 -> 12966641
    int*    bsum = ebuf + 800000;                // 256    -> 13766641
    ushort* wnb  = (ushort*)(ws + 13766912);     // 40960 ushorts (16B-aligned base)
    ushort* Wl0b = wnb;
    ushort* Wr0b = wnb + 8192;
    ushort* rW0b = wnb + 16384;
    ushort* Wl1b = wnb + 24576;
    ushort* Wr1b = wnb + 28672;
    ushort* Wl2b = wnb + 32768;
    ushort* Wr2b = wnb + 36864;
    float*  bn   = ws + 13787392;                // 384 floats (3 layer stat pairs)
    float*  bnsum0 = bn,       *bnsq0 = bn + 64;
    float*  bnsum1 = bn + 128, *bnsq1 = bn + 192;
    float*  bnsum2 = bn + 256, *bnsq2 = bn + 320;

    // ---- 1: fused prep ----
    prep_all_kernel<<<485, 256, 0, stream>>>(W1, W2, Wl0, Wr0, rW0, Wl1, Wr1, Wl2, Wr2,
                                             W1b, W2b, wnb, icnt, bn);
    // ---- 2-5: CSR build ----
    count_kernel<<<NE / 256, 256, 0, stream>>>(tgt, icnt);
    scanA_kernel<<<NBLK, 256, 0, stream>>>(icnt, off, bsum);
    scanB_kernel<<<NBLK, 256, 0, stream>>>(icnt, bsum, off, woff);
    fill_kernel<<<NE / 256, 256, 0, stream>>>(src, tgt, woff, ebuf);

    // ---- 6-7: layer 0 ----
    proj0_mfma_kernel<<<391, 256, 0, stream>>>(x, Wl0b, Wr0b, rW0b, bl0, rb0, xb, pre, res);
    gather_bn_kernel<<<2048, 256, 0, stream>>>(off, ebuf, xb, pre, bnsum0, bnsq0);

    // ---- 8-9: apply L0 + proj L1 (fused), gather L1 ----
    apply_proj_kernel<<<391, 256, 0, stream>>>(pre, res, bnsum0, bnsq0, g0, be0,
                                               hbuf, Wl1b, Wr1b, bl1, xb, pre);
    gather_bn_kernel<<<2048, 256, 0, stream>>>(off, ebuf, xb, pre, bnsum1, bnsq1);

    // ---- 10-11: apply L1 + proj L2 (fused), gather L2 ----
    apply_proj_kernel<<<391, 256, 0, stream>>>(pre, hbuf, bnsum1, bnsq1, g1, be1,
                                               hbuf, Wl2b, Wr2b, bl2, xb, pre);
    gather_bn_kernel<<<2048, 256, 0, stream>>>(off, ebuf, xb, pre, bnsum2, bnsq2);

    // ---- 12: final apply -> hb ----
    apply_final_kernel<<<1024, 256, 0, stream>>>(pre, hbuf, bnsum2, bnsq2, g2, be2, hb);

    // ---- 13: edge MLP ----
    edge_mlp_wave_kernel<<<EMG, 512, 0, stream>>>(hb, src, tgt, W1b, W2b, b1, b2, W3, b3, out);
}

// Round 21
// 381.654 us; speedup vs baseline: 1.1449x; 1.1449x over previous
//
#include <hip/hip_runtime.h>
#include <hip/hip_bf16.h>

#define NN 50000
#define NE 800000
#define HID 64
#define EPSV 1e-5f
#define NBLK 196            // ceil(NN/256)

typedef __attribute__((ext_vector_type(8))) short bf16x8;
typedef __attribute__((ext_vector_type(4))) float f32x4;
typedef __attribute__((ext_vector_type(4))) int int4v;

__device__ __forceinline__ ushort f2b(float f) {
    union { __hip_bfloat16 b; ushort u; } c;
    c.b = __float2bfloat16(f);
    return c.u;
}
__device__ __forceinline__ float b2f(ushort u) {
    return __uint_as_float(((unsigned int)u) << 16);
}

// ---------------- fused prep: all weight cvts + icnt zero + bn zero ----------------
__global__ void prep_all_kernel(
    const float* __restrict__ W1, const float* __restrict__ W2,
    const float* __restrict__ Wl0, const float* __restrict__ Wr0, const float* __restrict__ rW0,
    const float* __restrict__ Wl1, const float* __restrict__ Wr1,
    const float* __restrict__ Wl2, const float* __restrict__ Wr2,
    ushort* __restrict__ W1b, ushort* __restrict__ W2b,
    ushort* __restrict__ wnb, int* __restrict__ icnt, float* __restrict__ bnbuf)
{
    int i = blockIdx.x * 256 + threadIdx.x;
    if      (i < 16384)  W1b[i] = f2b(W1[i]);
    else if (i < 32768)  W2b[i - 16384] = f2b(W2[i - 16384]);
    else if (i < 40960)  wnb[i - 32768] = f2b(Wl0[i - 32768]);
    else if (i < 49152)  wnb[i - 32768] = f2b(Wr0[i - 40960]);
    else if (i < 57344)  wnb[i - 32768] = f2b(rW0[i - 49152]);
    else if (i < 61440)  wnb[i - 32768] = f2b(Wl1[i - 57344]);
    else if (i < 65536)  wnb[i - 32768] = f2b(Wr1[i - 61440]);
    else if (i < 69632)  wnb[i - 32768] = f2b(Wl2[i - 65536]);
    else if (i < 73728)  wnb[i - 32768] = f2b(Wr2[i - 69632]);
    else if (i < 123728) icnt[i - 73728] = 0;
    else if (i < 124112) bnbuf[i - 123728] = 0.f;
}

// ---------------- CSR build ----------------
__global__ void count_kernel(const int* __restrict__ tgt, int* __restrict__ icnt) {
    int e = blockIdx.x * 256 + threadIdx.x;
    if (e < NE) atomicAdd(&icnt[tgt[e]], 1);
}

__global__ void scanA_kernel(const int* __restrict__ icnt, int* __restrict__ off,
                             int* __restrict__ bsum) {
    __shared__ int s[256];
    const int t = threadIdx.x;
    const int i = blockIdx.x * 256 + t;
    int v = (i < NN) ? icnt[i] : 0;
    s[t] = v;
    __syncthreads();
    for (int d = 1; d < 256; d <<= 1) {
        int x = (t >= d) ? s[t - d] : 0;
        __syncthreads();
        s[t] += x;
        __syncthreads();
    }
    if (i < NN) off[i] = s[t];             // inclusive, block-local
    if (t == 255) bsum[blockIdx.x] = s[255];
}

__global__ void scanB_kernel(const int* __restrict__ icnt, const int* __restrict__ bsum,
                             int* __restrict__ off, int* __restrict__ woff) {
    __shared__ int red[256];
    const int t = threadIdx.x, bid = blockIdx.x;
    int s = 0;
    for (int j = t; j < bid; j += 256) s += bsum[j];
    red[t] = s;
    __syncthreads();
    for (int d = 128; d > 0; d >>= 1) {
        if (t < d) red[t] += red[t + d];
        __syncthreads();
    }
    const int bpre = red[0];
    const int i = bid * 256 + t;
    if (i < NN) {
        int e = off[i] - icnt[i] + bpre;
        off[i] = e;
        woff[i] = e;
        if (i == NN - 1) off[NN] = NE;
    }
}

__global__ void fill_kernel(const int* __restrict__ src, const int* __restrict__ tgt,
                            int* __restrict__ woff, int* __restrict__ ebuf) {
    int e = blockIdx.x * 256 + threadIdx.x;
    if (e < NE) {
        int p = atomicAdd(&woff[tgt[e]], 1);
        ebuf[p] = src[e];
    }
}

// ---------------- layer-0 projection: staged x-tile, 3 segs fused ----------------
__global__ __launch_bounds__(256) void proj0_mfma_kernel(
    const float* __restrict__ x,
    const ushort* __restrict__ w0, const ushort* __restrict__ w1,
    const ushort* __restrict__ w2,
    const float* __restrict__ bias1, const float* __restrict__ bias2,
    ushort* __restrict__ xb, float* __restrict__ pre, float* __restrict__ res)
{
    __shared__ ushort xt[128 * 128];    // 32 KB swizzled bf16 x-tile
    __shared__ float sC[128][65];
    const int tid = threadIdx.x;
    const int wv = tid >> 6, lane = tid & 63;
    const int l15 = lane & 15, l4 = lane >> 4;
    const int n0 = blockIdx.x * 128;

    {
        const int rloc = tid >> 1;
        int row = n0 + rloc; if (row > NN - 1) row = NN - 1;
        const int c0 = (tid & 1) * 64;
        #pragma unroll
        for (int gq = 0; gq < 8; gq++) {
            int c = c0 + gq * 8;
            float4 f0 = *(const float4*)&x[(long)row * 128 + c];
            float4 f1 = *(const float4*)&x[(long)row * 128 + c + 4];
            union { ushort u[8]; int4v v; } a;
            a.u[0] = f2b(f0.x); a.u[1] = f2b(f0.y); a.u[2] = f2b(f0.z); a.u[3] = f2b(f0.w);
            a.u[4] = f2b(f1.x); a.u[5] = f2b(f1.y); a.u[6] = f2b(f1.z); a.u[7] = f2b(f1.w);
            int byte = rloc * 256 + ((c * 2) ^ ((rloc & 7) << 4));
            *(int4v*)((char*)xt + byte) = a.v;
        }
    }
    __syncthreads();

    for (int seg = 0; seg < 3; seg++) {
        const ushort* W = (seg == 0) ? w0 : ((seg == 1) ? w1 : w2);
        bf16x8 wf[4][4];
        #pragma unroll
        for (int n = 0; n < 4; n++)
            #pragma unroll
            for (int ks = 0; ks < 4; ks++)
                wf[n][ks] = *(const bf16x8*)&W[(n * 16 + l15) * 128 + ks * 32 + l4 * 8];

        f32x4 acc[2][4];
        #pragma unroll
        for (int m = 0; m < 2; m++)
            #pragma unroll
            for (int n = 0; n < 4; n++)
                acc[m][n] = (f32x4){0.f, 0.f, 0.f, 0.f};

        #pragma unroll
        for (int m = 0; m < 2; m++) {
            const int row = wv * 32 + m * 16 + l15;
            #pragma unroll
            for (int ks = 0; ks < 4; ks++) {
                int byte = row * 256 + ((ks * 64 + l4 * 16) ^ ((row & 7) << 4));
                bf16x8 a = *(const bf16x8*)((const char*)xt + byte);
                #pragma unroll
                for (int n = 0; n < 4; n++)
                    acc[m][n] = __builtin_amdgcn_mfma_f32_16x16x32_bf16(a, wf[n][ks], acc[m][n], 0, 0, 0);
            }
        }
        #pragma unroll
        for (int m = 0; m < 2; m++)
            #pragma unroll
            for (int n = 0; n < 4; n++)
                #pragma unroll
                for (int r = 0; r < 4; r++)
                    sC[wv * 32 + m * 16 + l4 * 4 + r][n * 16 + l15] = acc[m][n][r];
        __syncthreads();

        const int r = tid >> 1, ch = (tid & 1) * 32;
        const int node = n0 + r;
        if (node < NN) {
            if (seg == 0) {
                #pragma unroll
                for (int gq = 0; gq < 4; gq++) {
                    union { ushort u[8]; int4v v; } pk;
                    #pragma unroll
                    for (int j = 0; j < 8; j++)
                        pk.u[j] = f2b(sC[r][ch + gq * 8 + j]);
                    *(int4v*)&xb[(long)node * 64 + ch + gq * 8] = pk.v;
                }
            } else {
                float* O = (seg == 1) ? pre : res;
                const float* bp = (seg == 1) ? bias1 : bias2;
                #pragma unroll
                for (int gq = 0; gq < 8; gq++) {
                    int c = ch + gq * 4;
                    float4 v = make_float4(sC[r][c + 0] + bp[c + 0], sC[r][c + 1] + bp[c + 1],
                                           sC[r][c + 2] + bp[c + 2], sC[r][c + 3] + bp[c + 3]);
                    *(float4*)&O[(long)node * 64 + c] = v;
                }
            }
        }
        __syncthreads();
    }
}

// ---------------- gather v2.1: 8-edge-wide vectorized + index-load pipelining ----------------
__global__ __launch_bounds__(256) void gather_bn_kernel(
    const int* __restrict__ off, const int* __restrict__ ebuf,
    const ushort* __restrict__ xb,
    float* __restrict__ vbase,
    float* __restrict__ bnsum, float* __restrict__ bnsq)
{
    __shared__ float r1[4][64], r2[4][64];
    const int lane = threadIdx.x & 63;
    const int wid = __builtin_amdgcn_readfirstlane(threadIdx.x >> 6);
    const int eslot = lane >> 3;
    const int cg = lane & 7;
    float s8[8], q8[8];
    #pragma unroll
    for (int j = 0; j < 8; j++) { s8[j] = 0.f; q8[j] = 0.f; }

    for (int n = blockIdx.x * 4 + wid; n < NN; n += gridDim.x * 4) {
        const int a = off[n], b = off[n + 1];
        float acc[8];
        #pragma unroll
        for (int j = 0; j < 8; j++) acc[j] = 0.f;
        int p = a + eslot;
        int sidx = (p < b) ? ebuf[p] : 0;
        for (; p < b; ) {
            int pn = p + 8;
            int nidx = (pn < b) ? ebuf[pn] : 0;      // index for NEXT round in flight
            union { int4v v; ushort u[8]; } cv;
            cv.v = *(const int4v*)&xb[(long)sidx * 64 + cg * 8];
            #pragma unroll
            for (int j = 0; j < 8; j++) acc[j] += b2f(cv.u[j]);
            p = pn; sidx = nidx;
        }
        #pragma unroll
        for (int m = 8; m <= 32; m <<= 1)
            #pragma unroll
            for (int j = 0; j < 8; j++)
                acc[j] += __shfl_xor(acc[j], m);
        if (eslot == 0) {
            const float inv_deg = 1.0f / fmaxf((float)(b - a), 1.f);
            float4 p0 = *(const float4*)&vbase[(long)n * 64 + cg * 8];
            float4 p1 = *(const float4*)&vbase[(long)n * 64 + cg * 8 + 4];
            float v[8];
            v[0] = acc[0] * inv_deg + p0.x; v[1] = acc[1] * inv_deg + p0.y;
            v[2] = acc[2] * inv_deg + p0.z; v[3] = acc[3] * inv_deg + p0.w;
            v[4] = acc[4] * inv_deg + p1.x; v[5] = acc[5] * inv_deg + p1.y;
            v[6] = acc[6] * inv_deg + p1.z; v[7] = acc[7] * inv_deg + p1.w;
            *(float4*)&vbase[(long)n * 64 + cg * 8]     = make_float4(v[0], v[1], v[2], v[3]);
            *(float4*)&vbase[(long)n * 64 + cg * 8 + 4] = make_float4(v[4], v[5], v[6], v[7]);
            #pragma unroll
            for (int j = 0; j < 8; j++) { s8[j] += v[j]; q8[j] += v[j] * v[j]; }
        }
    }
    if (eslot == 0) {
        #pragma unroll
        for (int j = 0; j < 8; j++) {
            r1[wid][cg * 8 + j] = s8[j];
            r2[wid][cg * 8 + j] = q8[j];
        }
    }
    __syncthreads();
    if (threadIdx.x < 64) {
        float s = r1[0][lane] + r1[1][lane] + r1[2][lane] + r1[3][lane];
        float q = r2[0][lane] + r2[1][lane] + r2[2][lane] + r2[3][lane];
        atomicAdd(&bnsum[lane], s);
        atomicAdd(&bnsq[lane], q);
    }
}

// ---------------- fused: BN-apply(layer i) + proj(layer i+1) ----------------
__global__ __launch_bounds__(256) void apply_proj_kernel(
    const float* __restrict__ vIn,
    const float* __restrict__ resb,
    const float* __restrict__ bnsum, const float* __restrict__ bnsq,
    const float* __restrict__ g, const float* __restrict__ be,
    float* __restrict__ hout,
    const ushort* __restrict__ Wl, const ushort* __restrict__ Wr,
    const float* __restrict__ bias,
    ushort* __restrict__ xb, float* __restrict__ preOut)
{
    __shared__ float scs[64], shs[64];
    __shared__ ushort tile[128 * 72];
    __shared__ float sC[128][65];
    const int tid = threadIdx.x;
    const int n0 = blockIdx.x * 128;
    const int wv = tid >> 6, lane = tid & 63;
    const int l15 = lane & 15, l4 = lane >> 4;

    if (tid < 64) {
        const float inv_n = 1.0f / (float)NN;
        float mu = bnsum[tid] * inv_n;
        float var = bnsq[tid] * inv_n - mu * mu;
        float rstd = rsqrtf(var + EPSV);
        float sc = g[tid] * rstd;
        scs[tid] = sc;
        shs[tid] = be[tid] - mu * sc;
    }
    __syncthreads();

    {
        const int rloc = tid >> 1;
        const int n = n0 + rloc;
        const int ch = (tid & 1) * 32;
        if (n < NN) {
            #pragma unroll
            for (int gq = 0; gq < 4; gq++) {
                int c = ch + gq * 8;
                float4 v0 = *(const float4*)&vIn[(long)n * 64 + c];
                float4 v1 = *(const float4*)&vIn[(long)n * 64 + c + 4];
                float4 r0 = *(const float4*)&resb[(long)n * 64 + c];
                float4 r1 = *(const float4*)&resb[(long)n * 64 + c + 4];
                float o[8];
                o[0] = fmaxf(fmaf(v0.x, scs[c + 0], shs[c + 0]), 0.f) + r0.x;
                o[1] = fmaxf(fmaf(v0.y, scs[c + 1], shs[c + 1]), 0.f) + r0.y;
                o[2] = fmaxf(fmaf(v0.z, scs[c + 2], shs[c + 2]), 0.f) + r0.z;
                o[3] = fmaxf(fmaf(v0.w, scs[c + 3], shs[c + 3]), 0.f) + r0.w;
                o[4] = fmaxf(fmaf(v1.x, scs[c + 4], shs[c + 4]), 0.f) + r1.x;
                o[5] = fmaxf(fmaf(v1.y, scs[c + 5], shs[c + 5]), 0.f) + r1.y;
                o[6] = fmaxf(fmaf(v1.z, scs[c + 6], shs[c + 6]), 0.f) + r1.z;
                o[7] = fmaxf(fmaf(v1.w, scs[c + 7], shs[c + 7]), 0.f) + r1.w;
                *(float4*)&hout[(long)n * 64 + c]     = make_float4(o[0], o[1], o[2], o[3]);
                *(float4*)&hout[(long)n * 64 + c + 4] = make_float4(o[4], o[5], o[6], o[7]);
                union { ushort u[8]; int4v v; } pk;
                #pragma unroll
                for (int j = 0; j < 8; j++) pk.u[j] = f2b(o[j]);
                int byte = rloc * 144 + ((c * 2) ^ ((rloc & 7) << 4));
                *(int4v*)((char*)tile + byte) = pk.v;
            }
        }
    }
    __syncthreads();

    for (int seg = 0; seg < 2; seg++) {
        const ushort* W = seg ? Wr : Wl;
        bf16x8 wf[4][2];
        #pragma unroll
        for (int n = 0; n < 4; n++)
            #pragma unroll
            for (int ks = 0; ks < 2; ks++)
                wf[n][ks] = *(const bf16x8*)&W[(n * 16 + l15) * 64 + ks * 32 + l4 * 8];

        f32x4 acc[2][4];
        #pragma unroll
        for (int m = 0; m < 2; m++)
            #pragma unroll
            for (int n = 0; n < 4; n++)
                acc[m][n] = (f32x4){0.f, 0.f, 0.f, 0.f};

        #pragma unroll
        for (int m = 0; m < 2; m++) {
            const int row = wv * 32 + m * 16 + l15;
            #pragma unroll
            for (int ks = 0; ks < 2; ks++) {
                int byte = row * 144 + ((((ks * 32 + l4 * 8) * 2)) ^ ((row & 7) << 4));
                bf16x8 a = *(const bf16x8*)((const char*)tile + byte);
                #pragma unroll
                for (int n = 0; n < 4; n++)
                    acc[m][n] = __builtin_amdgcn_mfma_f32_16x16x32_bf16(a, wf[n][ks], acc[m][n], 0, 0, 0);
            }
        }
        #pragma unroll
        for (int m = 0; m < 2; m++)
            #pragma unroll
            for (int n = 0; n < 4; n++)
                #pragma unroll
                for (int r = 0; r < 4; r++)
                    sC[wv * 32 + m * 16 + l4 * 4 + r][n * 16 + l15] = acc[m][n][r];
        __syncthreads();

        const int r = tid >> 1, ch = (tid & 1) * 32;
        const int node = n0 + r;
        if (node < NN) {
            if (seg == 0) {
                #pragma unroll
                for (int gq = 0; gq < 4; gq++) {
                    union { ushort u[8]; int4v v; } pk;
                    #pragma unroll
                    for (int j = 0; j < 8; j++)
                        pk.u[j] = f2b(sC[r][ch + gq * 8 + j]);
                    *(int4v*)&xb[(long)node * 64 + ch + gq * 8] = pk.v;
                }
            } else {
                #pragma unroll
                for (int gq = 0; gq < 8; gq++) {
                    int c = ch + gq * 4;
                    float4 v = make_float4(sC[r][c + 0] + bias[c + 0], sC[r][c + 1] + bias[c + 1],
                                           sC[r][c + 2] + bias[c + 2], sC[r][c + 3] + bias[c + 3]);
                    *(float4*)&preOut[(long)node * 64 + c] = v;
                }
            }
        }
        __syncthreads();
    }
}

// ---------------- final BN apply -> hb (bf16) only ----------------
__global__ void apply_final_kernel(const float* __restrict__ vIn,
                                   const float* __restrict__ resb,
                                   const float* __restrict__ bnsum, const float* __restrict__ bnsq,
                                   const float* __restrict__ g, const float* __restrict__ be,
                                   ushort* __restrict__ hb)
{
    const float inv_n = 1.0f / (float)NN;
    const int stride = gridDim.x * 256;
    for (int i = blockIdx.x * 256 + threadIdx.x; i < NN * 16; i += stride) {
        int n = i >> 4;
        int c0 = (i & 15) * 4;
        float sc[4], sh[4];
        #pragma unroll
        for (int j = 0; j < 4; j++) {
            int c = c0 + j;
            float mu = bnsum[c] * inv_n;
            float var = bnsq[c] * inv_n - mu * mu;
            float rstd = rsqrtf(var + EPSV);
            sc[j] = g[c] * rstd;
            sh[j] = be[c] - mu * sc[j];
        }
        float4 v = *(const float4*)&vIn[(long)n * 64 + c0];
        float4 r = *(const float4*)&resb[(long)n * 64 + c0];
        union { ushort u[4]; uint2 v2; } p;
        p.u[0] = f2b(fmaxf(fmaf(v.x, sc[0], sh[0]), 0.f) + r.x);
        p.u[1] = f2b(fmaxf(fmaf(v.y, sc[1], sh[1]), 0.f) + r.y);
        p.u[2] = f2b(fmaxf(fmaf(v.z, sc[2], sh[2]), 0.f) + r.z);
        p.u[3] = f2b(fmaxf(fmaf(v.w, sc[3], sh[3]), 0.f) + r.w);
        *(uint2*)&hb[(long)n * 64 + c0] = p.v2;
    }
}

// ---------------- edge MLP: barrier-free wave strips, SWAPPED L1 (R15-measured, 66us) ----------------
#define NSTRIP 25000        // NE / 32
#define EMG 256
#define ZSTR 136            // z1 row stride in ushorts (272 B, 16B-aligned)

#define GATHER(ss)                                                        \
    do {                                                                  \
        int e0g = (ss) * 32;                                              \
        _Pragma("unroll")                                                 \
        for (int m = 0; m < 2; m++) {                                     \
            int e = e0g + m * 16 + l15;                                   \
            const ushort* hs = hb + (long)src[e] * 64;                    \
            const ushort* ht = hb + (long)tgt[e] * 64;                    \
            ga[m][0] = *(const bf16x8*)&hs[l4 * 8];                       \
            ga[m][1] = *(const bf16x8*)&hs[32 + l4 * 8];                  \
            ga[m][2] = *(const bf16x8*)&ht[l4 * 8];                       \
            ga[m][3] = *(const bf16x8*)&ht[32 + l4 * 8];                  \
        }                                                                 \
    } while (0)

__global__ __launch_bounds__(512) void edge_mlp_wave_kernel(
    const ushort* __restrict__ hb,
    const int* __restrict__ src, const int* __restrict__ tgt,
    const ushort* __restrict__ W1b, const ushort* __restrict__ W2b,
    const float* __restrict__ b1, const float* __restrict__ b2,
    const float* __restrict__ W3, const float* __restrict__ b3,
    float* __restrict__ out)
{
    __shared__ ushort wlds[32768];        // [layer][oc][k], 16B-chunk XOR swizzle
    __shared__ ushort z1[8][32 * ZSTR];   // wave-private Z1 slices

    const int tid = threadIdx.x;
    const int wid = tid >> 6, lane = tid & 63;
    const int l15 = lane & 15, l4 = lane >> 4;

    for (int c = tid; c < 4096; c += 512) {
        int layer = c >> 11, oc = (c >> 4) & 127, kc = c & 15;
        const ushort* Wsrc = layer ? W2b : W1b;
        int4v v = *(const int4v*)&Wsrc[oc * 128 + kc * 8];
        int byte = layer * 32768 + oc * 256 + ((kc * 16) ^ ((oc & 7) << 4));
        *(int4v*)((char*)wlds + byte) = v;
    }

    // L1 bias as oc-quads (swapped C-layout: row=oc=n*16+l4*4+r)
    float4 b1q[8];
    float b2v[8], w3v[8];
    #pragma unroll
    for (int n = 0; n < 8; n++) {
        b1q[n] = *(const float4*)&b1[n * 16 + l4 * 4];
        int oc = n * 16 + l15;
        b2v[n] = b2[oc]; w3v[n] = W3[oc];
    }
    const float b3v = b3[0];

    const int bid = blockIdx.x;
    const int q = NSTRIP / EMG, r = NSTRIP % EMG;    // 97, 168
    const int t0 = bid * q + (bid < r ? bid : r);
    const int nt = q + (bid < r ? 1 : 0);
    ushort* zw = z1[wid];

    bf16x8 ga[2][4];
    if (wid < nt) GATHER(t0 + wid);
    __syncthreads();                      // wlds ready (only barrier)

    for (int j = wid; j < nt; j += 8) {
        const int e0 = (t0 + j) * 32;

        // ---- layer 1 (SWAPPED operands): C col=edge, row=oc ----
        f32x4 acc[2][8];
        #pragma unroll
        for (int m = 0; m < 2; m++)
            #pragma unroll
            for (int n = 0; n < 8; n++)
                acc[m][n] = (f32x4){b1q[n].x, b1q[n].y, b1q[n].z, b1q[n].w};
        #pragma unroll
        for (int ks = 0; ks < 4; ks++) {
            bf16x8 wf[8];
            #pragma unroll
            for (int n = 0; n < 8; n++) {
                int oc = n * 16 + l15;
                int byte = oc * 256 + (((ks * 4 + l4) * 16) ^ ((oc & 7) << 4));
                wf[n] = *(const bf16x8*)((const char*)wlds + byte);
            }
            #pragma unroll
            for (int m = 0; m < 2; m++)
                #pragma unroll
                for (int n = 0; n < 8; n++)
                    acc[m][n] = __builtin_amdgcn_mfma_f32_16x16x32_bf16(wf[n], ga[m][ks], acc[m][n], 0, 0, 0);
        }
        // Z1 = relu(acc): lane holds 4 consecutive oc for ONE edge -> b64 writes
        #pragma unroll
        for (int m = 0; m < 2; m++)
            #pragma unroll
            for (int n = 0; n < 8; n++) {
                union { ushort u[4]; uint2 d; } pk;
                #pragma unroll
                for (int rr = 0; rr < 4; rr++)
                    pk.u[rr] = f2b(fmaxf(acc[m][n][rr], 0.f));
                *(uint2*)&zw[(m * 16 + l15) * ZSTR + n * 16 + l4 * 4] = pk.d;
            }

        if (j + 8 < nt) GATHER(t0 + j + 8);

        // ---- layer 2 (unswapped) ----
        f32x4 acc2[2][8];
        #pragma unroll
        for (int m = 0; m < 2; m++)
            #pragma unroll
            for (int n = 0; n < 8; n++)
                acc2[m][n] = (f32x4){b2v[n], b2v[n], b2v[n], b2v[n]};
        #pragma unroll
        for (int ks = 0; ks < 4; ks++) {
            bf16x8 wf[8];
            #pragma unroll
            for (int n = 0; n < 8; n++) {
                int oc = n * 16 + l15;
                int byte = 32768 + oc * 256 + (((ks * 4 + l4) * 16) ^ ((oc & 7) << 4));
                wf[n] = *(const bf16x8*)((const char*)wlds + byte);
            }
            bf16x8 a2[2];
            #pragma unroll
            for (int m = 0; m < 2; m++)
                a2[m] = *(const bf16x8*)&zw[(m * 16 + l15) * ZSTR + ks * 32 + l4 * 8];
            #pragma unroll
            for (int m = 0; m < 2; m++)
                #pragma unroll
                for (int n = 0; n < 8; n++)
                    acc2[m][n] = __builtin_amdgcn_mfma_f32_16x16x32_bf16(a2[m], wf[n], acc2[m][n], 0, 0, 0);
        }

        // ---- layer 3 ----
        #pragma unroll
        for (int m = 0; m < 2; m++) {
            float sv[4];
            #pragma unroll
            for (int rr = 0; rr < 4; rr++) {
                float s = 0.f;
                #pragma unroll
                for (int n = 0; n < 8; n++)
                    s = fmaf(fmaxf(acc2[m][n][rr], 0.f), w3v[n], s);
                s += __shfl_xor(s, 1);
                s += __shfl_xor(s, 2);
                s += __shfl_xor(s, 4);
                s += __shfl_xor(s, 8);
                sv[rr] = s + b3v;
            }
            if (l15 == 0)
                *(float4*)&out[e0 + m * 16 + l4 * 4] =
                    make_float4(sv[0], sv[1], sv[2], sv[3]);
        }
    }
}

// ---------------- launch ----------------
extern "C" void kernel_launch(void* const* d_in, const int* in_sizes, int n_in,
                              void* d_out, int out_size, void* d_ws, size_t ws_size,
                              hipStream_t stream)
{
    const float* x   = (const float*)d_in[0];
    const int*   ei  = (const int*)d_in[1];
    const int* src = ei;
    const int* tgt = ei + NE;
    const float* Wl0 = (const float*)d_in[2];
    const float* bl0 = (const float*)d_in[3];
    const float* Wr0 = (const float*)d_in[4];
    const float* g0  = (const float*)d_in[5];
    const float* be0 = (const float*)d_in[6];
    const float* rW0 = (const float*)d_in[7];
    const float* rb0 = (const float*)d_in[8];
    const float* Wl1 = (const float*)d_in[9];
    const float* bl1 = (const float*)d_in[10];
    const float* Wr1 = (const float*)d_in[11];
    const float* g1  = (const float*)d_in[12];
    const float* be1 = (const float*)d_in[13];
    const float* Wl2 = (const float*)d_in[14];
    const float* bl2 = (const float*)d_in[15];
    const float* Wr2 = (const float*)d_in[16];
    const float* g2  = (const float*)d_in[17];
    const float* be2 = (const float*)d_in[18];
    const float* W1  = (const float*)d_in[19];
    const float* b1  = (const float*)d_in[20];
    const float* W2  = (const float*)d_in[21];
    const float* b2  = (const float*)d_in[22];
    const float* W3  = (const float*)d_in[23];
    const float* b3  = (const float*)d_in[24];
    float* out = (float*)d_out;

    float* ws = (float*)d_ws;
    float*  pre  = ws;                           // [0, 3.2M)
    float*  res  = ws + 3200000;                 // [3.2M, 6.4M)
    float*  hbuf = ws + 6400000;                 // [6.4M, 9.6M)
    ushort* xb   = (ushort*)(ws + 9600256);      // floats [9600256, 11200256)
    ushort* hb   = (ushort*)(ws + 11200256);     // floats [11200256, 12800256)
    ushort* W1b  = (ushort*)(ws + 12800256);     // floats [12800256, 12808448)
    ushort* W2b  = W1b + 16384;                  // floats [12808448, 12816640)
    int*    icnt = (int*)(ws + 12816640);        // 50000
    int*    off  = icnt + 50000;                 // 50001 -> 12866640
    int*    woff = off + 50001;                  // 50000 -> 12916641
    int*    ebuf = woff + 50000;                 // 800000 -> 12966641
    int*    bsum = ebuf + 800000;                // 256    -> 13766641
    ushort* wnb  = (ushort*)(ws + 13766912);     // 40960 ushorts (16B-aligned base)
    ushort* Wl0b = wnb;
    ushort* Wr0b = wnb + 8192;
    ushort* rW0b = wnb + 16384;
    ushort* Wl1b = wnb + 24576;
    ushort* Wr1b = wnb + 28672;
    ushort* Wl2b = wnb + 32768;
    ushort* Wr2b = wnb + 36864;
    float*  bn   = ws + 13787392;                // 384 floats (3 layer stat pairs)
    float*  bnsum0 = bn,       *bnsq0 = bn + 64;
    float*  bnsum1 = bn + 128, *bnsq1 = bn + 192;
    float*  bnsum2 = bn + 256, *bnsq2 = bn + 320;

    // ---- 1: fused prep ----
    prep_all_kernel<<<485, 256, 0, stream>>>(W1, W2, Wl0, Wr0, rW0, Wl1, Wr1, Wl2, Wr2,
                                             W1b, W2b, wnb, icnt, bn);
    // ---- 2-5: CSR build ----
    count_kernel<<<NE / 256, 256, 0, stream>>>(tgt, icnt);
    scanA_kernel<<<NBLK, 256, 0, stream>>>(icnt, off, bsum);
    scanB_kernel<<<NBLK, 256, 0, stream>>>(icnt, bsum, off, woff);
    fill_kernel<<<NE / 256, 256, 0, stream>>>(src, tgt, woff, ebuf);

    // ---- 6-7: layer 0 ----
    proj0_mfma_kernel<<<391, 256, 0, stream>>>(x, Wl0b, Wr0b, rW0b, bl0, rb0, xb, pre, res);
    gather_bn_kernel<<<1024, 256, 0, stream>>>(off, ebuf, xb, pre, bnsum0, bnsq0);

    // ---- 8-9: apply L0 + proj L1 (fused), gather L1 ----
    apply_proj_kernel<<<391, 256, 0, stream>>>(pre, res, bnsum0, bnsq0, g0, be0,
                                               hbuf, Wl1b, Wr1b, bl1, xb, pre);
    gather_bn_kernel<<<1024, 256, 0, stream>>>(off, ebuf, xb, pre, bnsum1, bnsq1);

    // ---- 10-11: apply L1 + proj L2 (fused), gather L2 ----
    apply_proj_kernel<<<391, 256, 0, stream>>>(pre, hbuf, bnsum1, bnsq1, g1, be1,
                                               hbuf, Wl2b, Wr2b, bl2, xb, pre);
    gather_bn_kernel<<<1024, 256, 0, stream>>>(off, ebuf, xb, pre, bnsum2, bnsq2);

    // ---- 12: final apply -> hb ----
    apply_final_kernel<<<1024, 256, 0, stream>>>(pre, hbuf, bnsum2, bnsq2, g2, be2, hb);

    // ---- 13: edge MLP ----
    edge_mlp_wave_kernel<<<EMG, 512, 0, stream>>>(hb, src, tgt, W1b, W2b, b1, b2, W3, b3, out);
}